// Round 17
// baseline (282.138 us; speedup 1.0000x reference)
//
#include <hip/hip_runtime.h>
#include <stdint.h>

typedef __bf16 bf16_t;
typedef __bf16 bf16x4_t __attribute__((ext_vector_type(4)));
typedef __bf16 bf16x8_t __attribute__((ext_vector_type(8)));
typedef float  f32x4_t  __attribute__((ext_vector_type(4)));

#define S_LEN 2048
#define DMODEL 1024
#define NHEAD 16
#define HDIM 64
#define MTOT 4096   // B*S
#define NT 32       // K/V tiles of 64
#define WBLK 4864   // per-wave LDS elems: K[2] 2048 | V[2] 2048 | P 768

__device__ __forceinline__ f32x4_t mfma16(bf16x8_t a, bf16x8_t b, f32x4_t c){
  return __builtin_amdgcn_mfma_f32_16x16x32_bf16(a, b, c, 0, 0, 0);
}

__device__ __forceinline__ void gload_lds16(const bf16_t* g, bf16_t* l){
  __builtin_amdgcn_global_load_lds(
      (const __attribute__((address_space(1))) void*)(uintptr_t)g,
      (__attribute__((address_space(3))) void*)(uintptr_t)l,
      16, 0, 0);
}

// ---- XOR-swizzled [ROWS][64] staging (linear LDS dest, pre-swizzled source) ----
template<int ROWS>
__device__ __forceinline__ void stage_tile(bf16_t* lds, const bf16_t* __restrict__ g,
                                           int ldg, int wid, int lane){
  const int rl = lane >> 3;
  const int cs = ((lane & 7) ^ rl) << 3;
#pragma unroll
  for (int it = 0; it < ROWS/32; ++it){
    const int chunk = it*4 + wid;
    gload_lds16(g + (size_t)(chunk*8 + rl)*ldg + cs, lds + chunk*512);
  }
}

// wave-level [16][64] slice (2 gload_lds), same swizzle
__device__ __forceinline__ void stage_slice16(bf16_t* lds, const bf16_t* __restrict__ g,
                                              int lane){
  const int rl = lane >> 3;
  const int cs = ((lane & 7) ^ rl) << 3;
#pragma unroll
  for (int c = 0; c < 2; ++c)
    gload_lds16(g + (size_t)(c*8 + rl)*HDIM + cs, lds + c*512);
}

// wave-level V slice, LDS layout [2 jh][64 d][8 j] (16B rows -> no bank clash).
__device__ __forceinline__ void stage_v(bf16_t* lds, const bf16_t* __restrict__ g,
                                        int lane){
#pragma unroll
  for (int c = 0; c < 2; ++c)
    gload_lds16(g + (size_t)lane*64 + c*8, lds + c*512);
}

__device__ __forceinline__ bf16x8_t lds_read8(const bf16_t* t, int row, int ko){
  return *(const bf16x8_t*)&t[row*64 + (ko ^ ((row & 7) << 3))];
}

__device__ __forceinline__ bf16x8_t sq8(bf16x8_t v){
  bf16x8_t r;
#pragma unroll
  for (int i=0;i<8;i++){ float f = (float)v[i]; r[i] = (bf16_t)(f*f); }
  return r;
}

// ---------------- K0: f32 -> bf16 cast, all 5 inputs in ONE launch ----------
__global__ __launch_bounds__(256)
void vsa_cast_all_kernel(const float* __restrict__ x,  const float* __restrict__ Wq,
                         const float* __restrict__ Wk, const float* __restrict__ Wv,
                         const float* __restrict__ Wo,
                         bf16_t* __restrict__ xb, bf16_t* __restrict__ Wb){
  const int i = blockIdx.x*256 + threadIdx.x;   // 0 .. 2097151
  const float* src; bf16_t* dst; int off;
  if (i < 1048576){
    src = x;  dst = xb; off = i;
  } else {
    const int j = i - 1048576;
    off = j & 262143;
    const int wsel = j >> 18;                    // 0..3
    if      (wsel == 0){ src = Wq; dst = Wb; }
    else if (wsel == 1){ src = Wk; dst = Wb + (size_t)1*1048576; }
    else if (wsel == 2){ src = Wv; dst = Wb + (size_t)2*1048576; }
    else               { src = Wo; dst = Wb + (size_t)3*1048576; }
  }
  float4 v = ((const float4*)src)[off];
  bf16x4_t o = {(bf16_t)v.x,(bf16_t)v.y,(bf16_t)v.z,(bf16_t)v.w};
  ((bf16x4_t*)dst)[off] = o;
}

// ---------------- K1: QKV projection, plain bf16 GEMM ----------------
// For z=Q,K the MFMA operands are SWAPPED (bit-identical products, transposed
// D placement): lane holds 4 consecutive d at fixed s -> 8B coalesced stores.
__global__ __launch_bounds__(256)
void vsa_qkv_kernel(const bf16_t* __restrict__ xb, const bf16_t* __restrict__ Wb,
                    bf16_t* __restrict__ Qb, bf16_t* __restrict__ Kb,
                    bf16_t* __restrict__ Vblk)
{
  __shared__ __align__(16) bf16_t Ah[128][64], Bh[128][64];
  const int z  = blockIdx.z;                 // 0=Q,1=K,2=V
  const int m0 = blockIdx.x * 128;
  const int n0 = blockIdx.y * 128;
  const int tid = threadIdx.x, lane = tid & 63, wid = tid >> 6;
  const int wr = (wid >> 1) * 64, wc = (wid & 1) * 64;
  const bf16_t* Wz = Wb + (size_t)z * (DMODEL*DMODEL);

  const f32x4_t zz = {0.f,0.f,0.f,0.f};
  f32x4_t acc[4][4];
#pragma unroll
  for (int i=0;i<4;i++)
#pragma unroll
    for (int j=0;j<4;j++) acc[i][j] = zz;

  for (int kt = 0; kt < 16; ++kt){
    const int k0 = kt * 64;
    stage_tile<128>(&Ah[0][0], xb + (size_t)m0*DMODEL + k0, DMODEL, wid, lane);
    stage_tile<128>(&Bh[0][0], Wz + (size_t)n0*DMODEL + k0, DMODEL, wid, lane);
    __syncthreads();
#pragma unroll
    for (int kk = 0; kk < 2; ++kk){
      const int ko = kk*32 + (lane>>4)*8;
      bf16x8_t ah[4], bh4[4];
#pragma unroll
      for (int i=0;i<4;i++){
        ah[i]  = lds_read8(&Ah[0][0], wr + i*16 + (lane&15), ko);
        bh4[i] = lds_read8(&Bh[0][0], wc + i*16 + (lane&15), ko);
      }
      if (z == 2){
#pragma unroll
        for (int i=0;i<4;i++)
#pragma unroll
          for (int j=0;j<4;j++)
            acc[i][j] = mfma16(ah[i], bh4[j], acc[i][j]);
      } else {
#pragma unroll
        for (int i=0;i<4;i++)
#pragma unroll
          for (int j=0;j<4;j++)
            acc[i][j] = mfma16(bh4[j], ah[i], acc[i][j]);   // swapped
      }
    }
    __syncthreads();
  }

  if (z == 2){
#pragma unroll
    for (int i=0;i<4;i++)
#pragma unroll
      for (int j=0;j<4;j++)
#pragma unroll
        for (int r=0;r<4;r++){
          const int m = m0 + wr + i*16 + ((lane>>4)<<2) + r;
          const int n = n0 + wc + j*16 + (lane&15);
          const float q = acc[i][j][r];
          const int b = m >> 11, s = m & 2047, h = n >> 6, d = n & 63;
          const size_t bh_ = (size_t)b*NHEAD + h;
          // V block-transposed: [bh][s/64][64 d][64 j]
          Vblk[bh_*(size_t)(S_LEN*HDIM) + (size_t)(s>>6)*4096 + d*64 + (s&63)] = (bf16_t)q;
        }
  } else {
    bf16_t* dst0 = (z == 0) ? Qb : Kb;
#pragma unroll
    for (int i=0;i<4;i++)
#pragma unroll
      for (int j=0;j<4;j++){
        // swapped D: row (cg*4+r) = W-row (d), col (lane&15) = x-row (s)
        const int m = m0 + wr + i*16 + (lane & 15);           // s index
        const int n = n0 + wc + j*16 + ((lane>>4)<<2);        // d base, 4 consecutive
        const int b = m >> 11, s = m & 2047, h = n >> 6, d = n & 63;
        const size_t bh_ = (size_t)b*NHEAD + h;
        bf16x4_t o4 = {(bf16_t)acc[i][j][0], (bf16_t)acc[i][j][1],
                       (bf16_t)acc[i][j][2], (bf16_t)acc[i][j][3]};
        *(bf16x4_t*)&dst0[(bh_*S_LEN + s)*HDIM + d] = o4;     // 8B aligned store
      }
  }
}

// ---------------- K2: attention, barrier-free wave-owned j-slices ----------
// Round-14 kernel verbatim (best known): r8 structure + NT Wout stores.
// K^2 in-register; store-aware counted vmcnt: loads(jt)[4] issued a full
// iteration before stores(jt-1)[8] -> vmcnt(12) retires exactly loads(jt).
__global__ __launch_bounds__(256, 4)
void vsa_attn_kernel(const bf16_t* __restrict__ Qb,
                     const bf16_t* __restrict__ Kb,
                     const bf16_t* __restrict__ Vblk,
                     float* __restrict__ Wout,
                     bf16_t* __restrict__ o1)
{
  __shared__ __align__(16) bf16_t smem[4*WBLK];
  __shared__ float lred[4][2][16];

  const int lin = blockIdx.x;               // 0..2047
  const int xcd = lin & 7;
  const int idx = lin >> 3;                 // 0..255
  const int qt  = idx & 63;                 // 64 q-tiles of 32 rows
  const int bh  = xcd + 8*(idx >> 6);       // 4 heads per XCD -> K/V L2-resident
  const int lane = threadIdx.x & 63, w = (int)(threadIdx.x >> 6);
  const int qr = lane & 15, cg = lane >> 4;

  const size_t base = (size_t)bh * (S_LEN*HDIM);
  const bf16_t* Kg = Kb   + base + (size_t)(w*16)*HDIM;
  const bf16_t* Vg = Vblk + base + w*16;    // wave's 16-j column window

  bf16_t* Kbuf = smem + w*WBLK;             // [2][16][64] swizzled
  bf16_t* Vbuf = Kbuf + 2048;               // [2][2 jh][64 d][8 j]
  bf16_t* Pbuf = Vbuf + 2048;               // 2 qh x [16 i][24]

  // Q fragments (2 q-subtiles x 2 kk) + squared*64 (folds the 1/8 score scale)
  bf16x8_t aq[2][2], aq2[2][2];
#pragma unroll
  for (int qh = 0; qh < 2; ++qh){
    const bf16_t* qrow = Qb + base + (size_t)(qt*32 + qh*16 + qr)*HDIM;
#pragma unroll
    for (int kk = 0; kk < 2; ++kk){
      aq[qh][kk] = *(const bf16x8_t*)(qrow + kk*32 + cg*8);
      bf16x8_t t;
#pragma unroll
      for (int e=0;e<8;e++){ float f = (float)aq[qh][kk][e]; t[e] = (bf16_t)(64.f*f*f); }
      aq2[qh][kk] = t;
    }
  }

  // ---- pass 1: row sums (scores are cosine-bounded: no max tracking) ----
  float lp[2][4] = {{0.f,0.f,0.f,0.f},{0.f,0.f,0.f,0.f}};
  stage_slice16(Kbuf, Kg, lane);
  for (int jt = 0; jt < NT; ++jt){
    const int nb = (jt+1) & (NT-1);          // wrap-prefetch keeps counts uniform
    __builtin_amdgcn_sched_barrier(0);
    stage_slice16(Kbuf + ((jt+1)&1)*1024, Kg + (size_t)nb*64*HDIM, lane);  // [+2]
    asm volatile("s_waitcnt vmcnt(2)" ::: "memory");   // K(jt) landed; prefetch in flight
    __builtin_amdgcn_sched_barrier(0);
    const bf16_t* kb = Kbuf + (jt&1)*1024;
    bf16x8_t kf0  = lds_read8(kb, qr, cg*8), kf1 = lds_read8(kb, qr, 32+cg*8);
    bf16x8_t k2f0 = sq8(kf0),                k2f1 = sq8(kf1);
    f32x4_t nu[2], nr[2];
    __builtin_amdgcn_s_setprio(1);
#pragma unroll
    for (int qh = 0; qh < 2; ++qh){
      f32x4_t a = {0.f,0.f,0.f,0.f}, b = {0.f,0.f,0.f,0.f};
      a = mfma16(aq[qh][0],  kf0,  a); a = mfma16(aq[qh][1],  kf1,  a);
      b = mfma16(aq2[qh][0], k2f0, b); b = mfma16(aq2[qh][1], k2f1, b);
      nu[qh] = a; nr[qh] = b;
    }
    __builtin_amdgcn_s_setprio(0);
#pragma unroll
    for (int qh = 0; qh < 2; ++qh)
#pragma unroll
      for (int r=0;r<4;r++){
        const float s = nu[qh][r]*rsqrtf(fmaxf(nr[qh][r], 6.4e-15f));
        lp[qh][r] += __expf(s);
      }
  }

  // cross-lane (16 qr) + cross-wave (4 j-slices) l reduce
#pragma unroll
  for (int qh=0;qh<2;qh++)
#pragma unroll
    for (int r=0;r<4;r++){
      float l = lp[qh][r];
      l += __shfl_xor(l,1); l += __shfl_xor(l,2);
      l += __shfl_xor(l,4); l += __shfl_xor(l,8);
      lred[w][qh][cg*4+r] = l;
    }
  __syncthreads();                          // barrier #1 (drains all DMA; K tile0 in buf0)
  float rl[2][4];
#pragma unroll
  for (int qh=0;qh<2;qh++)
#pragma unroll
    for (int r=0;r<4;r++)
      rl[qh][r] = 1.0f/(lred[0][qh][cg*4+r]+lred[1][qh][cg*4+r]
                       +lred[2][qh][cg*4+r]+lred[3][qh][cg*4+r]);

  // ---- pass 2: weights + PV ----
  const f32x4_t zz = {0.f,0.f,0.f,0.f};
  f32x4_t oacc[2][4];
#pragma unroll
  for (int qh=0;qh<2;qh++)
#pragma unroll
    for (int n=0;n<4;n++) oacc[qh][n] = zz;
  const size_t wb = (size_t)bh * S_LEN * S_LEN;
  const bf16x8_t zero8 = {};

  // prologue: V(0) (K(0) already in Kbuf[0] via pass-1 wrap prefetch)
  stage_v(Vbuf, Vg, lane);
  asm volatile("s_waitcnt vmcnt(0)" ::: "memory");
  __builtin_amdgcn_sched_barrier(0);

  for (int jt = 0; jt < NT; ++jt){
    const int nb = (jt+1) & (NT-1);
    __builtin_amdgcn_sched_barrier(0);
    stage_slice16(Kbuf + ((jt+1)&1)*1024, Kg + (size_t)nb*64*HDIM, lane);  // [+2]
    stage_v(Vbuf + ((jt+1)&1)*1024, Vg + (size_t)nb*4096, lane);           // [+2]
    // steady state: loads(jt)[4, oldest] < stores(jt-1)[8] < loads(jt+1)[4]
    asm volatile("s_waitcnt vmcnt(12)" ::: "memory");  // K/V(jt) landed
    __builtin_amdgcn_sched_barrier(0);
    const bf16_t* kb = Kbuf + (jt&1)*1024;
    bf16x8_t kf0  = lds_read8(kb, qr, cg*8), kf1 = lds_read8(kb, qr, 32+cg*8);
    bf16x8_t k2f0 = sq8(kf0),                k2f1 = sq8(kf1);
    f32x4_t nu[2], nr[2];
    __builtin_amdgcn_s_setprio(1);
#pragma unroll
    for (int qh = 0; qh < 2; ++qh){
      f32x4_t a = {0.f,0.f,0.f,0.f}, b = {0.f,0.f,0.f,0.f};
      a = mfma16(aq[qh][0],  kf0,  a); a = mfma16(aq[qh][1],  kf1,  a);
      b = mfma16(aq2[qh][0], k2f0, b); b = mfma16(aq2[qh][1], k2f1, b);
      nu[qh] = a; nr[qh] = b;
    }
    __builtin_amdgcn_s_setprio(0);
#pragma unroll
    for (int qh = 0; qh < 2; ++qh)
#pragma unroll
      for (int r=0;r<4;r++){
        const float s = nu[qh][r]*rsqrtf(fmaxf(nr[qh][r], 6.4e-15f));
        const float wgt = __expf(s) * rl[qh][r];
        const int i = qt*32 + qh*16 + cg*4 + r;
        const int j = jt*64 + w*16 + qr;
        __builtin_nontemporal_store(wgt, Wout + wb + (size_t)i*S_LEN + j);  // [8 NT stores]
        Pbuf[qh*384 + (cg*4+r)*24 + qr] = (bf16_t)wgt;
      }
    asm volatile("s_waitcnt lgkmcnt(0)" ::: "memory");  // P writes visible to own wave
    __builtin_amdgcn_sched_barrier(0);
    // PV: D[i,d] = sum_j P[i,j] V[j,d]; K=32 MFMA, A zero-padded on cg>=2
    const int k0 = (cg & 1) * 8;
    bf16x8_t pa0 = (cg < 2) ? *(const bf16x8_t*)&Pbuf[      qr*24 + k0] : zero8;
    bf16x8_t pa1 = (cg < 2) ? *(const bf16x8_t*)&Pbuf[384 + qr*24 + k0] : zero8;
    const bf16_t* vbase = Vbuf + (jt&1)*1024 + (cg&1)*512;   // jh = k0>>3
    __builtin_amdgcn_s_setprio(1);
#pragma unroll
    for (int n=0;n<4;n++){
      bf16x8_t vb = *(const bf16x8_t*)&vbase[(n*16+qr)*8];
      oacc[0][n] = mfma16(pa0, vb, oacc[0][n]);
      oacc[1][n] = mfma16(pa1, vb, oacc[1][n]);
    }
    __builtin_amdgcn_s_setprio(0);
  }

  // ---- O reduce across the 4 j-slice waves, then epilogue ----
  asm volatile("s_waitcnt vmcnt(0)" ::: "memory");      // drain wrap-stage DMA before reuse
  __builtin_amdgcn_sched_barrier(0);
  float* Ow = (float*)Kbuf;                             // own wave block, stride 68 (pad)
#pragma unroll
  for (int qh=0;qh<2;qh++)
#pragma unroll
    for (int n=0;n<4;n++)
#pragma unroll
      for (int r=0;r<4;r++)
        Ow[(qh*16+cg*4+r)*68 + n*16+qr] = oacc[qh][n][r];
  __syncthreads();                          // barrier #2
  {
    const int row = lane >> 1;              // 0..31
    const int jl  = (lane & 1)*8;
    float v[8];
#pragma unroll
    for (int e=0;e<8;e++) v[e] = 0.f;
#pragma unroll
    for (int ww=0; ww<4; ++ww){
      const float* Os = (const float*)(smem + ww*WBLK);
#pragma unroll
      for (int e=0;e<8;e++) v[e] += Os[row*68 + w*16 + jl + e];
    }
    const int b = bh >> 4, h = bh & 15;
    const int srow = qt*32 + row;
    const size_t o = ((size_t)b*S_LEN + srow)*DMODEL + (size_t)h*HDIM + w*16 + jl;
    bf16x8_t hv;
#pragma unroll
    for (int e=0;e<8;e++) hv[e] = (bf16_t)v[e];
    *(bf16x8_t*)(o1 + o) = hv;
  }
}

// ---------------- K3: output projection, 128x128 tile (QKV structure), ------
// swapped operands -> lane holds 4 consecutive n at fixed m -> f32x4 NT stores.
__global__ __launch_bounds__(256)
void vsa_oproj_kernel(const bf16_t* __restrict__ Ab, const bf16_t* __restrict__ Bb,
                      float* __restrict__ out)
{
  __shared__ __align__(16) bf16_t Ah[128][64], Bh[128][64];
  const int m0 = blockIdx.x * 128;
  const int n0 = blockIdx.y * 128;
  const int tid = threadIdx.x, lane = tid & 63, wid = tid >> 6;
  const int wr = (wid >> 1) * 64, wc = (wid & 1) * 64;

  const f32x4_t zz = {0.f,0.f,0.f,0.f};
  f32x4_t acc[4][4];
#pragma unroll
  for (int i=0;i<4;i++)
#pragma unroll
    for (int j=0;j<4;j++) acc[i][j] = zz;

  for (int kt = 0; kt < 16; ++kt){
    const int k0 = kt * 64;
    stage_tile<128>(&Ah[0][0], Ab + (size_t)m0*DMODEL + k0, DMODEL, wid, lane);
    stage_tile<128>(&Bh[0][0], Bb + (size_t)n0*DMODEL + k0, DMODEL, wid, lane);
    __syncthreads();
#pragma unroll
    for (int kk = 0; kk < 2; ++kk){
      const int ko = kk*32 + (lane>>4)*8;
      bf16x8_t ah[4], bh4[4];
#pragma unroll
      for (int i=0;i<4;i++){
        ah[i]  = lds_read8(&Ah[0][0], wr + i*16 + (lane&15), ko);
        bh4[i] = lds_read8(&Bh[0][0], wc + i*16 + (lane&15), ko);
      }
#pragma unroll
      for (int i=0;i<4;i++)
#pragma unroll
        for (int j=0;j<4;j++)
          acc[i][j] = mfma16(bh4[j], ah[i], acc[i][j]);   // swapped
    }
    __syncthreads();
  }

#pragma unroll
  for (int i=0;i<4;i++)
#pragma unroll
    for (int j=0;j<4;j++){
      // swapped D: row (cg*4+r) = B-row (n), col (lane&15) = A-row (m)
      const int m = m0 + wr + i*16 + (lane & 15);
      const int n = n0 + wc + j*16 + ((lane>>4)<<2);      // 4 consecutive n
      f32x4_t o4 = {acc[i][j][0], acc[i][j][1], acc[i][j][2], acc[i][j][3]};
      __builtin_nontemporal_store(o4, (f32x4_t*)(out + (size_t)m*DMODEL + n));
    }
}

extern "C" void kernel_launch(void* const* d_in, const int* in_sizes, int n_in,
                              void* d_out, int out_size, void* d_ws, size_t ws_size,
                              hipStream_t stream)
{
  const float* x  = (const float*)d_in[0];
  const float* Wq = (const float*)d_in[1];
  const float* Wk = (const float*)d_in[2];
  const float* Wv = (const float*)d_in[3];
  const float* Wo = (const float*)d_in[4];
  float* out  = (float*)d_out;
  float* attw = out + (size_t)MTOT*DMODEL;   // tuple output 1: [B,H,S,S]

  // workspace layout (bf16 elements, each slab 4194304 elts = 8 MB)
  bf16_t* ws = (bf16_t*)d_ws;
  const size_t C = 4194304;
  bf16_t* xb   = ws;
  bf16_t* Wb   = ws + C;     // [4][1024*1024] order q,k,v,o
  bf16_t* Qb   = ws + 2*C;
  bf16_t* Kb   = ws + 3*C;
  bf16_t* Vblk = ws + 4*C;
  bf16_t* o1   = ws + 5*C;

  const size_t W1 = 1048576;  // DMODEL*DMODEL

  // one cast launch for x + all 4 weights (2,097,152 float4s)
  vsa_cast_all_kernel<<<8192, 256, 0, stream>>>(x, Wq, Wk, Wv, Wo, xb, Wb);

  vsa_qkv_kernel<<<dim3(32, 8, 3), 256, 0, stream>>>(xb, Wb, Qb, Kb, Vblk);
  vsa_attn_kernel<<<dim3(2048), 256, 0, stream>>>(Qb, Kb, Vblk, attw, o1);
  vsa_oproj_kernel<<<dim3(32, 8), 256, 0, stream>>>(o1, Wb + 3*W1, out);
}

// Round 18
// 276.275 us; speedup vs baseline: 1.0212x; 1.0212x over previous
//
#include <hip/hip_runtime.h>
#include <stdint.h>

typedef __bf16 bf16_t;
typedef __bf16 bf16x4_t __attribute__((ext_vector_type(4)));
typedef __bf16 bf16x8_t __attribute__((ext_vector_type(8)));
typedef float  f32x4_t  __attribute__((ext_vector_type(4)));

#define S_LEN 2048
#define DMODEL 1024
#define NHEAD 16
#define HDIM 64
#define MTOT 4096   // B*S
#define NT 32       // K/V tiles of 64
#define WBLK 4864   // per-wave LDS elems: K[2] 2048 | V[2] 2048 | P 768

__device__ __forceinline__ f32x4_t mfma16(bf16x8_t a, bf16x8_t b, f32x4_t c){
  return __builtin_amdgcn_mfma_f32_16x16x32_bf16(a, b, c, 0, 0, 0);
}

__device__ __forceinline__ void gload_lds16(const bf16_t* g, bf16_t* l){
  __builtin_amdgcn_global_load_lds(
      (const __attribute__((address_space(1))) void*)(uintptr_t)g,
      (__attribute__((address_space(3))) void*)(uintptr_t)l,
      16, 0, 0);
}

// ---- XOR-swizzled [ROWS][64] staging (linear LDS dest, pre-swizzled source) ----
template<int ROWS>
__device__ __forceinline__ void stage_tile(bf16_t* lds, const bf16_t* __restrict__ g,
                                           int ldg, int wid, int lane){
  const int rl = lane >> 3;
  const int cs = ((lane & 7) ^ rl) << 3;
#pragma unroll
  for (int it = 0; it < ROWS/32; ++it){
    const int chunk = it*4 + wid;
    gload_lds16(g + (size_t)(chunk*8 + rl)*ldg + cs, lds + chunk*512);
  }
}

// wave-level [16][64] slice (2 gload_lds), same swizzle
__device__ __forceinline__ void stage_slice16(bf16_t* lds, const bf16_t* __restrict__ g,
                                              int lane){
  const int rl = lane >> 3;
  const int cs = ((lane & 7) ^ rl) << 3;
#pragma unroll
  for (int c = 0; c < 2; ++c)
    gload_lds16(g + (size_t)(c*8 + rl)*HDIM + cs, lds + c*512);
}

// wave-level V slice, LDS layout [2 jh][64 d][8 j] (16B rows -> no bank clash).
__device__ __forceinline__ void stage_v(bf16_t* lds, const bf16_t* __restrict__ g,
                                        int lane){
#pragma unroll
  for (int c = 0; c < 2; ++c)
    gload_lds16(g + (size_t)lane*64 + c*8, lds + c*512);
}

__device__ __forceinline__ bf16x8_t lds_read8(const bf16_t* t, int row, int ko){
  return *(const bf16x8_t*)&t[row*64 + (ko ^ ((row & 7) << 3))];
}

__device__ __forceinline__ bf16x8_t sq8(bf16x8_t v){
  bf16x8_t r;
#pragma unroll
  for (int i=0;i<8;i++){ float f = (float)v[i]; r[i] = (bf16_t)(f*f); }
  return r;
}

// ---------------- K0: f32 -> bf16 cast, all 5 inputs in ONE launch ----------
__global__ __launch_bounds__(256)
void vsa_cast_all_kernel(const float* __restrict__ x,  const float* __restrict__ Wq,
                         const float* __restrict__ Wk, const float* __restrict__ Wv,
                         const float* __restrict__ Wo,
                         bf16_t* __restrict__ xb, bf16_t* __restrict__ Wb){
  const int i = blockIdx.x*256 + threadIdx.x;   // 0 .. 2097151
  const float* src; bf16_t* dst; int off;
  if (i < 1048576){
    src = x;  dst = xb; off = i;
  } else {
    const int j = i - 1048576;
    off = j & 262143;
    const int wsel = j >> 18;                    // 0..3
    if      (wsel == 0){ src = Wq; dst = Wb; }
    else if (wsel == 1){ src = Wk; dst = Wb + (size_t)1*1048576; }
    else if (wsel == 2){ src = Wv; dst = Wb + (size_t)2*1048576; }
    else               { src = Wo; dst = Wb + (size_t)3*1048576; }
  }
  float4 v = ((const float4*)src)[off];
  bf16x4_t o = {(bf16_t)v.x,(bf16_t)v.y,(bf16_t)v.z,(bf16_t)v.w};
  ((bf16x4_t*)dst)[off] = o;
}

// ---------------- K1: QKV projection, plain bf16 GEMM ----------------
// For z=Q,K the MFMA operands are SWAPPED (bit-identical products, transposed
// D placement): lane holds 4 consecutive d at fixed s -> 8B coalesced stores.
__global__ __launch_bounds__(256)
void vsa_qkv_kernel(const bf16_t* __restrict__ xb, const bf16_t* __restrict__ Wb,
                    bf16_t* __restrict__ Qb, bf16_t* __restrict__ Kb,
                    bf16_t* __restrict__ Vblk)
{
  __shared__ __align__(16) bf16_t Ah[128][64], Bh[128][64];
  const int z  = blockIdx.z;                 // 0=Q,1=K,2=V
  const int m0 = blockIdx.x * 128;
  const int n0 = blockIdx.y * 128;
  const int tid = threadIdx.x, lane = tid & 63, wid = tid >> 6;
  const int wr = (wid >> 1) * 64, wc = (wid & 1) * 64;
  const bf16_t* Wz = Wb + (size_t)z * (DMODEL*DMODEL);

  const f32x4_t zz = {0.f,0.f,0.f,0.f};
  f32x4_t acc[4][4];
#pragma unroll
  for (int i=0;i<4;i++)
#pragma unroll
    for (int j=0;j<4;j++) acc[i][j] = zz;

  for (int kt = 0; kt < 16; ++kt){
    const int k0 = kt * 64;
    stage_tile<128>(&Ah[0][0], xb + (size_t)m0*DMODEL + k0, DMODEL, wid, lane);
    stage_tile<128>(&Bh[0][0], Wz + (size_t)n0*DMODEL + k0, DMODEL, wid, lane);
    __syncthreads();
#pragma unroll
    for (int kk = 0; kk < 2; ++kk){
      const int ko = kk*32 + (lane>>4)*8;
      bf16x8_t ah[4], bh4[4];
#pragma unroll
      for (int i=0;i<4;i++){
        ah[i]  = lds_read8(&Ah[0][0], wr + i*16 + (lane&15), ko);
        bh4[i] = lds_read8(&Bh[0][0], wc + i*16 + (lane&15), ko);
      }
      if (z == 2){
#pragma unroll
        for (int i=0;i<4;i++)
#pragma unroll
          for (int j=0;j<4;j++)
            acc[i][j] = mfma16(ah[i], bh4[j], acc[i][j]);
      } else {
#pragma unroll
        for (int i=0;i<4;i++)
#pragma unroll
          for (int j=0;j<4;j++)
            acc[i][j] = mfma16(bh4[j], ah[i], acc[i][j]);   // swapped
      }
    }
    __syncthreads();
  }

  if (z == 2){
#pragma unroll
    for (int i=0;i<4;i++)
#pragma unroll
      for (int j=0;j<4;j++)
#pragma unroll
        for (int r=0;r<4;r++){
          const int m = m0 + wr + i*16 + ((lane>>4)<<2) + r;
          const int n = n0 + wc + j*16 + (lane&15);
          const float q = acc[i][j][r];
          const int b = m >> 11, s = m & 2047, h = n >> 6, d = n & 63;
          const size_t bh_ = (size_t)b*NHEAD + h;
          // V block-transposed: [bh][s/64][64 d][64 j]
          Vblk[bh_*(size_t)(S_LEN*HDIM) + (size_t)(s>>6)*4096 + d*64 + (s&63)] = (bf16_t)q;
        }
  } else {
    bf16_t* dst0 = (z == 0) ? Qb : Kb;
#pragma unroll
    for (int i=0;i<4;i++)
#pragma unroll
      for (int j=0;j<4;j++){
        // swapped D: row (cg*4+r) = W-row (d), col (lane&15) = x-row (s)
        const int m = m0 + wr + i*16 + (lane & 15);           // s index
        const int n = n0 + wc + j*16 + ((lane>>4)<<2);        // d base, 4 consecutive
        const int b = m >> 11, s = m & 2047, h = n >> 6, d = n & 63;
        const size_t bh_ = (size_t)b*NHEAD + h;
        bf16x4_t o4 = {(bf16_t)acc[i][j][0], (bf16_t)acc[i][j][1],
                       (bf16_t)acc[i][j][2], (bf16_t)acc[i][j][3]};
        *(bf16x4_t*)&dst0[(bh_*S_LEN + s)*HDIM + d] = o4;     // 8B aligned store
      }
  }
}

// ---------------- K2: attention, barrier-free wave-owned j-slices ----------
// Best-measured kernel (r14, 278.3 us): r8 structure + NT Wout stores.
// K^2 in-register; store-aware counted vmcnt: loads(jt)[4] issued a full
// iteration before stores(jt-1)[8] -> vmcnt(12) retires exactly loads(jt).
__global__ __launch_bounds__(256, 4)
void vsa_attn_kernel(const bf16_t* __restrict__ Qb,
                     const bf16_t* __restrict__ Kb,
                     const bf16_t* __restrict__ Vblk,
                     float* __restrict__ Wout,
                     bf16_t* __restrict__ o1)
{
  __shared__ __align__(16) bf16_t smem[4*WBLK];
  __shared__ float lred[4][2][16];

  const int lin = blockIdx.x;               // 0..2047
  const int xcd = lin & 7;
  const int idx = lin >> 3;                 // 0..255
  const int qt  = idx & 63;                 // 64 q-tiles of 32 rows
  const int bh  = xcd + 8*(idx >> 6);       // 4 heads per XCD -> K/V L2-resident
  const int lane = threadIdx.x & 63, w = (int)(threadIdx.x >> 6);
  const int qr = lane & 15, cg = lane >> 4;

  const size_t base = (size_t)bh * (S_LEN*HDIM);
  const bf16_t* Kg = Kb   + base + (size_t)(w*16)*HDIM;
  const bf16_t* Vg = Vblk + base + w*16;    // wave's 16-j column window

  bf16_t* Kbuf = smem + w*WBLK;             // [2][16][64] swizzled
  bf16_t* Vbuf = Kbuf + 2048;               // [2][2 jh][64 d][8 j]
  bf16_t* Pbuf = Vbuf + 2048;               // 2 qh x [16 i][24]

  // Q fragments (2 q-subtiles x 2 kk) + squared*64 (folds the 1/8 score scale)
  bf16x8_t aq[2][2], aq2[2][2];
#pragma unroll
  for (int qh = 0; qh < 2; ++qh){
    const bf16_t* qrow = Qb + base + (size_t)(qt*32 + qh*16 + qr)*HDIM;
#pragma unroll
    for (int kk = 0; kk < 2; ++kk){
      aq[qh][kk] = *(const bf16x8_t*)(qrow + kk*32 + cg*8);
      bf16x8_t t;
#pragma unroll
      for (int e=0;e<8;e++){ float f = (float)aq[qh][kk][e]; t[e] = (bf16_t)(64.f*f*f); }
      aq2[qh][kk] = t;
    }
  }

  // ---- pass 1: row sums (scores are cosine-bounded: no max tracking) ----
  float lp[2][4] = {{0.f,0.f,0.f,0.f},{0.f,0.f,0.f,0.f}};
  stage_slice16(Kbuf, Kg, lane);
  for (int jt = 0; jt < NT; ++jt){
    const int nb = (jt+1) & (NT-1);          // wrap-prefetch keeps counts uniform
    __builtin_amdgcn_sched_barrier(0);
    stage_slice16(Kbuf + ((jt+1)&1)*1024, Kg + (size_t)nb*64*HDIM, lane);  // [+2]
    asm volatile("s_waitcnt vmcnt(2)" ::: "memory");   // K(jt) landed; prefetch in flight
    __builtin_amdgcn_sched_barrier(0);
    const bf16_t* kb = Kbuf + (jt&1)*1024;
    bf16x8_t kf0  = lds_read8(kb, qr, cg*8), kf1 = lds_read8(kb, qr, 32+cg*8);
    bf16x8_t k2f0 = sq8(kf0),                k2f1 = sq8(kf1);
    f32x4_t nu[2], nr[2];
    __builtin_amdgcn_s_setprio(1);
#pragma unroll
    for (int qh = 0; qh < 2; ++qh){
      f32x4_t a = {0.f,0.f,0.f,0.f}, b = {0.f,0.f,0.f,0.f};
      a = mfma16(aq[qh][0],  kf0,  a); a = mfma16(aq[qh][1],  kf1,  a);
      b = mfma16(aq2[qh][0], k2f0, b); b = mfma16(aq2[qh][1], k2f1, b);
      nu[qh] = a; nr[qh] = b;
    }
    __builtin_amdgcn_s_setprio(0);
#pragma unroll
    for (int qh = 0; qh < 2; ++qh)
#pragma unroll
      for (int r=0;r<4;r++){
        const float s = nu[qh][r]*rsqrtf(fmaxf(nr[qh][r], 6.4e-15f));
        lp[qh][r] += __expf(s);
      }
  }

  // cross-lane (16 qr) + cross-wave (4 j-slices) l reduce
#pragma unroll
  for (int qh=0;qh<2;qh++)
#pragma unroll
    for (int r=0;r<4;r++){
      float l = lp[qh][r];
      l += __shfl_xor(l,1); l += __shfl_xor(l,2);
      l += __shfl_xor(l,4); l += __shfl_xor(l,8);
      lred[w][qh][cg*4+r] = l;
    }
  __syncthreads();                          // barrier #1 (drains all DMA; K tile0 in buf0)
  float rl[2][4];
#pragma unroll
  for (int qh=0;qh<2;qh++)
#pragma unroll
    for (int r=0;r<4;r++)
      rl[qh][r] = 1.0f/(lred[0][qh][cg*4+r]+lred[1][qh][cg*4+r]
                       +lred[2][qh][cg*4+r]+lred[3][qh][cg*4+r]);

  // ---- pass 2: weights + PV ----
  const f32x4_t zz = {0.f,0.f,0.f,0.f};
  f32x4_t oacc[2][4];
#pragma unroll
  for (int qh=0;qh<2;qh++)
#pragma unroll
    for (int n=0;n<4;n++) oacc[qh][n] = zz;
  const size_t wb = (size_t)bh * S_LEN * S_LEN;
  const bf16x8_t zero8 = {};

  // prologue: V(0) (K(0) already in Kbuf[0] via pass-1 wrap prefetch)
  stage_v(Vbuf, Vg, lane);
  asm volatile("s_waitcnt vmcnt(0)" ::: "memory");
  __builtin_amdgcn_sched_barrier(0);

  for (int jt = 0; jt < NT; ++jt){
    const int nb = (jt+1) & (NT-1);
    __builtin_amdgcn_sched_barrier(0);
    stage_slice16(Kbuf + ((jt+1)&1)*1024, Kg + (size_t)nb*64*HDIM, lane);  // [+2]
    stage_v(Vbuf + ((jt+1)&1)*1024, Vg + (size_t)nb*4096, lane);           // [+2]
    // steady state: loads(jt)[4, oldest] < stores(jt-1)[8] < loads(jt+1)[4]
    asm volatile("s_waitcnt vmcnt(12)" ::: "memory");  // K/V(jt) landed
    __builtin_amdgcn_sched_barrier(0);
    const bf16_t* kb = Kbuf + (jt&1)*1024;
    bf16x8_t kf0  = lds_read8(kb, qr, cg*8), kf1 = lds_read8(kb, qr, 32+cg*8);
    bf16x8_t k2f0 = sq8(kf0),                k2f1 = sq8(kf1);
    f32x4_t nu[2], nr[2];
    __builtin_amdgcn_s_setprio(1);
#pragma unroll
    for (int qh = 0; qh < 2; ++qh){
      f32x4_t a = {0.f,0.f,0.f,0.f}, b = {0.f,0.f,0.f,0.f};
      a = mfma16(aq[qh][0],  kf0,  a); a = mfma16(aq[qh][1],  kf1,  a);
      b = mfma16(aq2[qh][0], k2f0, b); b = mfma16(aq2[qh][1], k2f1, b);
      nu[qh] = a; nr[qh] = b;
    }
    __builtin_amdgcn_s_setprio(0);
#pragma unroll
    for (int qh = 0; qh < 2; ++qh)
#pragma unroll
      for (int r=0;r<4;r++){
        const float s = nu[qh][r]*rsqrtf(fmaxf(nr[qh][r], 6.4e-15f));
        const float wgt = __expf(s) * rl[qh][r];
        const int i = qt*32 + qh*16 + cg*4 + r;
        const int j = jt*64 + w*16 + qr;
        __builtin_nontemporal_store(wgt, Wout + wb + (size_t)i*S_LEN + j);  // [8 NT stores]
        Pbuf[qh*384 + (cg*4+r)*24 + qr] = (bf16_t)wgt;
      }
    asm volatile("s_waitcnt lgkmcnt(0)" ::: "memory");  // P writes visible to own wave
    __builtin_amdgcn_sched_barrier(0);
    // PV: D[i,d] = sum_j P[i,j] V[j,d]; K=32 MFMA, A zero-padded on cg>=2
    const int k0 = (cg & 1) * 8;
    bf16x8_t pa0 = (cg < 2) ? *(const bf16x8_t*)&Pbuf[      qr*24 + k0] : zero8;
    bf16x8_t pa1 = (cg < 2) ? *(const bf16x8_t*)&Pbuf[384 + qr*24 + k0] : zero8;
    const bf16_t* vbase = Vbuf + (jt&1)*1024 + (cg&1)*512;   // jh = k0>>3
    __builtin_amdgcn_s_setprio(1);
#pragma unroll
    for (int n=0;n<4;n++){
      bf16x8_t vb = *(const bf16x8_t*)&vbase[(n*16+qr)*8];
      oacc[0][n] = mfma16(pa0, vb, oacc[0][n]);
      oacc[1][n] = mfma16(pa1, vb, oacc[1][n]);
    }
    __builtin_amdgcn_s_setprio(0);
  }

  // ---- O reduce across the 4 j-slice waves, then epilogue ----
  asm volatile("s_waitcnt vmcnt(0)" ::: "memory");      // drain wrap-stage DMA before reuse
  __builtin_amdgcn_sched_barrier(0);
  float* Ow = (float*)Kbuf;                             // own wave block, stride 68 (pad)
#pragma unroll
  for (int qh=0;qh<2;qh++)
#pragma unroll
    for (int n=0;n<4;n++)
#pragma unroll
      for (int r=0;r<4;r++)
        Ow[(qh*16+cg*4+r)*68 + n*16+qr] = oacc[qh][n][r];
  __syncthreads();                          // barrier #2
  {
    const int row = lane >> 1;              // 0..31
    const int jl  = (lane & 1)*8;
    float v[8];
#pragma unroll
    for (int e=0;e<8;e++) v[e] = 0.f;
#pragma unroll
    for (int ww=0; ww<4; ++ww){
      const float* Os = (const float*)(smem + ww*WBLK);
#pragma unroll
      for (int e=0;e<8;e++) v[e] += Os[row*68 + w*16 + jl + e];
    }
    const int b = bh >> 4, h = bh & 15;
    const int srow = qt*32 + row;
    const size_t o = ((size_t)b*S_LEN + srow)*DMODEL + (size_t)h*HDIM + w*16 + jl;
    bf16x8_t hv;
#pragma unroll
    for (int e=0;e<8;e++) hv[e] = (bf16_t)v[e];
    *(bf16x8_t*)(o1 + o) = hv;
  }
}

// ---------------- K3: output projection, plain bf16, 64x128 tile ----------------
__global__ __launch_bounds__(256)
void vsa_oproj_kernel(const bf16_t* __restrict__ Ab, const bf16_t* __restrict__ Bb,
                      float* __restrict__ out)
{
  __shared__ __align__(16) bf16_t Ah[64][64], Bh[128][64];
  const int m0 = blockIdx.x * 64;
  const int n0 = blockIdx.y * 128;
  const int tid = threadIdx.x, lane = tid & 63, wid = tid >> 6;
  const int wc = wid * 32;

  const f32x4_t zz = {0.f,0.f,0.f,0.f};
  f32x4_t acc[4][2];
#pragma unroll
  for (int i=0;i<4;i++)
#pragma unroll
    for (int j=0;j<2;j++) acc[i][j] = zz;

  for (int kt = 0; kt < 16; ++kt){
    const int k0 = kt * 64;
    stage_tile<64> (&Ah[0][0], Ab + (size_t)m0*DMODEL + k0, DMODEL, wid, lane);
    stage_tile<128>(&Bh[0][0], Bb + (size_t)n0*DMODEL + k0, DMODEL, wid, lane);
    __syncthreads();
#pragma unroll
    for (int kk = 0; kk < 2; ++kk){
      const int ko = kk*32 + (lane>>4)*8;
      bf16x8_t ah[4], bh4[2];
#pragma unroll
      for (int i=0;i<4;i++)
        ah[i] = lds_read8(&Ah[0][0], i*16 + (lane&15), ko);
#pragma unroll
      for (int j=0;j<2;j++)
        bh4[j] = lds_read8(&Bh[0][0], wc + j*16 + (lane&15), ko);
#pragma unroll
      for (int i=0;i<4;i++)
#pragma unroll
        for (int j=0;j<2;j++)
          acc[i][j] = mfma16(ah[i], bh4[j], acc[i][j]);
    }
    __syncthreads();
  }

#pragma unroll
  for (int i=0;i<4;i++)
#pragma unroll
    for (int j=0;j<2;j++)
#pragma unroll
      for (int r=0;r<4;r++){
        const int m = m0 + i*16 + ((lane>>4)<<2) + r;
        const int n = n0 + wc + j*16 + (lane&15);
        out[(size_t)m*DMODEL + n] = acc[i][j][r];
      }
}

extern "C" void kernel_launch(void* const* d_in, const int* in_sizes, int n_in,
                              void* d_out, int out_size, void* d_ws, size_t ws_size,
                              hipStream_t stream)
{
  const float* x  = (const float*)d_in[0];
  const float* Wq = (const float*)d_in[1];
  const float* Wk = (const float*)d_in[2];
  const float* Wv = (const float*)d_in[3];
  const float* Wo = (const float*)d_in[4];
  float* out  = (float*)d_out;
  float* attw = out + (size_t)MTOT*DMODEL;   // tuple output 1: [B,H,S,S]

  // workspace layout (bf16 elements, each slab 4194304 elts = 8 MB)
  bf16_t* ws = (bf16_t*)d_ws;
  const size_t C = 4194304;
  bf16_t* xb   = ws;
  bf16_t* Wb   = ws + C;     // [4][1024*1024] order q,k,v,o
  bf16_t* Qb   = ws + 2*C;
  bf16_t* Kb   = ws + 3*C;
  bf16_t* Vblk = ws + 4*C;
  bf16_t* o1   = ws + 5*C;

  const size_t W1 = 1048576;  // DMODEL*DMODEL

  // one cast launch for x + all 4 weights (2,097,152 float4s)
  vsa_cast_all_kernel<<<8192, 256, 0, stream>>>(x, Wq, Wk, Wv, Wo, xb, Wb);

  vsa_qkv_kernel<<<dim3(32, 8, 3), 256, 0, stream>>>(xb, Wb, Qb, Kb, Vblk);
  vsa_attn_kernel<<<dim3(2048), 256, 0, stream>>>(Qb, Kb, Vblk, attw, o1);
  vsa_oproj_kernel<<<dim3(64, 8), 256, 0, stream>>>(o1, Wb + 3*W1, out);
}